// Round 16
// baseline (794.371 us; speedup 1.0000x reference)
//
#include <hip/hip_runtime.h>
#include <math.h>

#define BDIM 2
#define SEQ 512
#define DMODEL 768
#define NHEAD 12
#define HDIM 64
#define NLAYER 6
#define VOCAB 32000
#define MROWS (BDIM*SEQ)   // 1024
#define EPSV 1e-6f

typedef unsigned short u16;
typedef unsigned int u32;
typedef __bf16 bf16x8 __attribute__((ext_vector_type(8)));
typedef float f32x4 __attribute__((ext_vector_type(4)));

__device__ __forceinline__ u16 f2bf(float f) {
    union { float f; u32 u; } v; v.f = f;
    u32 r = v.u + 0x7fffu + ((v.u >> 16) & 1u);   // RNE
    return (u16)(r >> 16);
}
__device__ __forceinline__ float bf2f(u16 b) {
    union { u32 u; float f; } v; v.u = ((u32)b) << 16;
    return v.f;
}

// async global->LDS, 16B per lane, dest = wave-uniform base + lane*16
__device__ __forceinline__ void gload16(const u16* g, u16* l) {
    __builtin_amdgcn_global_load_lds(
        (const __attribute__((address_space(1))) unsigned int*)g,
        (__attribute__((address_space(3))) unsigned int*)l,
        16, 0, 0);
}

// ---------------- embedding (h stays fp32) ----------------
__global__ void embed_kernel(const int* __restrict__ x, const float* __restrict__ tok,
                             const float* __restrict__ pos, float* __restrict__ h) {
    int i = blockIdx.x * blockDim.x + threadIdx.x;
    if (i >= MROWS * DMODEL) return;
    int bs = i / DMODEL, d = i - bs * DMODEL;
    int s = bs & (SEQ - 1);
    h[i] = tok[(size_t)x[bs] * DMODEL + d] + pos[(size_t)s * DMODEL + d];
}

// ---------------- transpose + fp32->bf16: in[K][N] -> out[N][K], 64x64 tiles, vec IO ----------------
__global__ __launch_bounds__(256) void transpose_conv(const float* __restrict__ in, u16* __restrict__ out,
                                                      int K, int N, long in_bs, long out_bs) {
    __shared__ float t[64][65];
    int b = blockIdx.z;
    int n0 = blockIdx.x * 64, k0 = blockIdx.y * 64;
    int tid = threadIdx.x;
    const float* ip = in + (size_t)b * in_bs;
    int kr = tid >> 4, nc = (tid & 15) * 4;
    #pragma unroll
    for (int i = 0; i < 4; ++i) {
        float4 v = *(const float4*)(ip + (size_t)(k0 + kr + i * 16) * N + n0 + nc);
        t[kr + i * 16][nc] = v.x; t[kr + i * 16][nc + 1] = v.y;
        t[kr + i * 16][nc + 2] = v.z; t[kr + i * 16][nc + 3] = v.w;
    }
    __syncthreads();
    u16* op = out + (size_t)b * out_bs;
    int nr = tid >> 4, kc = (tid & 15) * 4;
    #pragma unroll
    for (int i = 0; i < 4; ++i) {
        ushort4 s;
        s.x = f2bf(t[kc + 0][nr + i * 16]);
        s.y = f2bf(t[kc + 1][nr + i * 16]);
        s.z = f2bf(t[kc + 2][nr + i * 16]);
        s.w = f2bf(t[kc + 3][nr + i * 16]);
        *(ushort4*)(op + (size_t)(n0 + nr + i * 16) * K + k0 + kc) = s;
    }
}

// merged transpose for the 4 square 768x768 weight families (z = layer*4 + which)
__global__ __launch_bounds__(256) void transpose_qkvo(const float* __restrict__ wq, const float* __restrict__ wk,
                                                      const float* __restrict__ wv, const float* __restrict__ wo,
                                                      u16* __restrict__ WtQKV, u16* __restrict__ WtO) {
    __shared__ float t[64][65];
    int z = blockIdx.z;
    int which = z & 3, l = z >> 2;
    const float* srcs[4] = {wq, wk, wv, wo};
    const float* ip = srcs[which] + (size_t)l * 768 * 768;
    u16* op = (which < 3) ? (WtQKV + (size_t)l * 2304 * 768 + (size_t)which * 768 * 768)
                          : (WtO + (size_t)l * 768 * 768);
    int n0 = blockIdx.x * 64, k0 = blockIdx.y * 64;
    int tid = threadIdx.x;
    int kr = tid >> 4, nc = (tid & 15) * 4;
    #pragma unroll
    for (int i = 0; i < 4; ++i) {
        float4 v = *(const float4*)(ip + (size_t)(k0 + kr + i * 16) * 768 + n0 + nc);
        t[kr + i * 16][nc] = v.x; t[kr + i * 16][nc + 1] = v.y;
        t[kr + i * 16][nc + 2] = v.z; t[kr + i * 16][nc + 3] = v.w;
    }
    __syncthreads();
    int nr = tid >> 4, kc = (tid & 15) * 4;
    #pragma unroll
    for (int i = 0; i < 4; ++i) {
        ushort4 s;
        s.x = f2bf(t[kc + 0][nr + i * 16]);
        s.y = f2bf(t[kc + 1][nr + i * 16]);
        s.z = f2bf(t[kc + 2][nr + i * 16]);
        s.w = f2bf(t[kc + 3][nr + i * 16]);
        *(ushort4*)(op + (size_t)(n0 + nr + i * 16) * 768 + k0 + kc) = s;
    }
}

// ---------------- DummyNorm: s*(x-mean)/(std_ddof1 + eps) + b ----------------
template<bool OUTBF>
__global__ __launch_bounds__(256) void norm_kernel(const float* __restrict__ in,
                                                   const float* __restrict__ scale,
                                                   const float* __restrict__ bias,
                                                   void* __restrict__ outp) {
    int row = blockIdx.x;
    const float* xr = in + (size_t)row * DMODEL;
    int t = threadIdx.x;
    float v0 = xr[t], v1 = xr[t + 256], v2 = xr[t + 512];

    float s = v0 + v1 + v2;
    for (int o = 32; o > 0; o >>= 1) s += __shfl_down(s, o);
    __shared__ float red1[4];
    __shared__ float red2[4];
    int wid = t >> 6, lane = t & 63;
    if (lane == 0) red1[wid] = s;
    __syncthreads();
    float mean = (red1[0] + red1[1] + red1[2] + red1[3]) * (1.0f / DMODEL);

    float d0 = v0 - mean, d1 = v1 - mean, d2 = v2 - mean;
    float ss = d0 * d0 + d1 * d1 + d2 * d2;
    for (int o = 32; o > 0; o >>= 1) ss += __shfl_xor(ss, o);
    if (lane == 0) red2[wid] = ss;
    __syncthreads();
    float var = (red2[0] + red2[1] + red2[2] + red2[3]) * (1.0f / (DMODEL - 1));
    float inv = 1.0f / (sqrtf(var) + EPSV);

    size_t o0 = (size_t)row * DMODEL + t;
    float r0 = scale[t] * d0 * inv + bias[t];
    float r1 = scale[t + 256] * d1 * inv + bias[t + 256];
    float r2 = scale[t + 512] * d2 * inv + bias[t + 512];
    if (OUTBF) {
        u16* out = (u16*)outp;
        out[o0] = f2bf(r0); out[o0 + 256] = f2bf(r1); out[o0 + 512] = f2bf(r2);
    } else {
        float* out = (float*)outp;
        out[o0] = r0; out[o0 + 256] = r1; out[o0 + 512] = r2;
    }
}

// ======================= bf16 MFMA GEMMs, global_load_lds + dbuf + XOR swizzle ==================

// ---------------- 128x128 head GEMM, BK=32, swapped-operand epilogue (float4 C stores) ----------
// Super-row layout: storage = 64 super-rows of 128B (2 logical rows each). Element (R,k):
//   byte = (R>>1)*128 + ((((R&1)<<2) + (k>>3)) ^ ((R>>1)&7))*16 + (k&7)*2
// MFMA called as D = Wt_frag x act_frag: D-row (reg rr) = 4 consecutive N cols -> float4 store.
__global__ __launch_bounds__(256) void gemm_hd(const u16* __restrict__ A,
                                               const u16* __restrict__ Wt,
                                               const float* __restrict__ bias,
                                               float* __restrict__ Cout,
                                               int M, int N, int K) {
    __shared__ u16 Alds[2][128 * 32];
    __shared__ u16 Blds[2][128 * 32];
    int tid = threadIdx.x;
    int lane = tid & 63;
    int wid = tid >> 6;
    int l15 = lane & 15, lk = lane >> 4;
    int wm = (wid >> 1) * 64, wn = (wid & 1) * 64;
    // XCD panel swizzle (grid 2000, %8==0)
    int id = blockIdx.x;
    int xcd = id & 7, jj = id >> 3;
    int g = xcd * ((int)gridDim.x >> 3) + jj;
    int mb = M >> 7;
    int bn = (g / mb) * 128;
    int bm = (g % mb) * 128;

    f32x4 acc[4][4];
    #pragma unroll
    for (int i = 0; i < 4; ++i)
        #pragma unroll
        for (int j = 0; j < 4; ++j) { f32x4 z = {0.f, 0.f, 0.f, 0.f}; acc[i][j] = z; }

    // fixed per-lane staging source
    int q  = (lane & 7) ^ (lane >> 3);
    int Rl = 2 * (lane >> 3) + (q >> 2);
    int cl = q & 3;
    const u16* gA = A  + (size_t)(bm + Rl) * K + cl * 8;
    const u16* gB = Wt + (size_t)(bn + Rl) * K + cl * 8;

    auto STAGE = [&](int buf, int k0) {
        #pragma unroll
        for (int i = 0; i < 2; ++i) {
            int rb = (wid * 2 + i) * 16;      // 16-row region
            gload16(gA + (size_t)rb * K + k0, &Alds[buf][rb * 32]);
            gload16(gB + (size_t)rb * K + k0, &Blds[buf][rb * 32]);
        }
    };

    STAGE(0, 0);
    __syncthreads();
    int nt = K >> 5;
    int cur = 0;
    for (int t = 0; t < nt; ++t) {
        if (t + 1 < nt) STAGE(cur ^ 1, (t + 1) << 5);

        bf16x8 af[4], bfv[4];
        #pragma unroll
        for (int mi = 0; mi < 4; ++mi) {
            int R = wm + mi * 16 + l15;
            int ci = ((((R & 1) << 2) + lk) ^ ((R >> 1) & 7));
            af[mi] = *(const bf16x8*)&Alds[cur][(R >> 1) * 64 + ci * 8];
        }
        #pragma unroll
        for (int ni = 0; ni < 4; ++ni) {
            int R = wn + ni * 16 + l15;
            int ci = ((((R & 1) << 2) + lk) ^ ((R >> 1) & 7));
            bfv[ni] = *(const bf16x8*)&Blds[cur][(R >> 1) * 64 + ci * 8];
        }
        // swapped operands: A-operand = weight frag -> D reg index spans N (consecutive cols)
        #pragma unroll
        for (int mi = 0; mi < 4; ++mi)
            #pragma unroll
            for (int ni = 0; ni < 4; ++ni)
                acc[mi][ni] = __builtin_amdgcn_mfma_f32_16x16x32_bf16(bfv[ni], af[mi], acc[mi][ni], 0, 0, 0);

        __syncthreads();   // drains vmcnt(0): next tile landed; cur free to overwrite
        cur ^= 1;
    }

    // Epilogue: lane holds row = l15 of act tile, 4 consecutive cols = lk*4+reg
    #pragma unroll
    for (int mi = 0; mi < 4; ++mi) {
        int row = bm + wm + mi * 16 + l15;
        #pragma unroll
        for (int ni = 0; ni < 4; ++ni) {
            int col = bn + wn + ni * 16 + lk * 4;
            float4 bv = *(const float4*)(bias + col);
            float4 st;
            st.x = acc[mi][ni][0] + bv.x;
            st.y = acc[mi][ni][1] + bv.y;
            st.z = acc[mi][ni][2] + bv.z;
            st.w = acc[mi][ni][3] + bv.w;
            *(float4*)(Cout + (size_t)row * N + col) = st;
        }
    }
}

// ---------------- BMxBN layer GEMMs, BK=64, 1-D grid + XCD panel-grouping swizzle ----------------
// LDS tiles LINEAR [rows][64] bf16. 16B chunk c8 of row r lives at chunk c8^(r&7) (involution,
// applied to the per-lane GLOBAL SOURCE at stage time and to the ds_read addr at use time).
template<bool OUTBF, bool BIAS, bool RES, bool GELU, int BM, int BN>
__global__ __launch_bounds__(256) void gemm_sm(const u16* __restrict__ A,
                                               const u16* __restrict__ Wt,
                                               const float* __restrict__ bias,
                                               const float* __restrict__ res,
                                               void* __restrict__ Cout,
                                               int M, int N, int K) {
    __shared__ u16 Alds[2][BM * 64];
    __shared__ u16 Blds[2][BN * 64];
    int tid = threadIdx.x;
    int lane = tid & 63;
    int wid = tid >> 6;
    int l15 = lane & 15, lk = lane >> 4;
    int wr = wid >> 1, wc = wid & 1;           // 2x2 waves; wave tile (BM/2)x(BN/2)
    int id = blockIdx.x;
    int xcd = id & 7, j = id >> 3;
    int g = xcd * ((int)gridDim.x >> 3) + j;
    int mb = M / BM;
    int bn = (g / mb) * BN;
    int bm = (g % mb) * BM;
    constexpr int MI = BM / 32;
    constexpr int NI = BN / 32;

    f32x4 acc[MI][NI];
    #pragma unroll
    for (int i = 0; i < MI; ++i)
        #pragma unroll
        for (int j2 = 0; j2 < NI; ++j2) { f32x4 z = {0.f, 0.f, 0.f, 0.f}; acc[i][j2] = z; }

    int lr  = lane >> 3;
    int lc8 = (lane & 7) ^ lr;
    const u16* gA = A  + (size_t)(bm + lr) * K + lc8 * 8;
    const u16* gB = Wt + (size_t)(bn + lr) * K + lc8 * 8;

    auto STAGE = [&](int buf, int k0) {
        #pragma unroll
        for (int i = 0; i < MI; ++i) {
            int rb = wid * (BM / 4) + i * 8;
            gload16(gA + (size_t)rb * K + k0, &Alds[buf][rb * 64]);
        }
        #pragma unroll
        for (int i = 0; i < NI; ++i) {
            int rb = wid * (BN / 4) + i * 8;
            gload16(gB + (size_t)rb * K + k0, &Blds[buf][rb * 64]);
        }
    };

    STAGE(0, 0);
    __syncthreads();
    int nt = K >> 6;
    int cur = 0;
    for (int t = 0; t < nt; ++t) {
        if (t + 1 < nt) STAGE(cur ^ 1, (t + 1) << 6);

        #pragma unroll
        for (int s = 0; s < 2; ++s) {
            bf16x8 af[MI], bfv[NI];
            #pragma unroll
            for (int mi = 0; mi < MI; ++mi) {
                int R = wr * (BM / 2) + mi * 16 + l15;
                af[mi] = *(const bf16x8*)&Alds[cur][R * 64 + (((s * 4 + lk) ^ (R & 7)) << 3)];
            }
            #pragma unroll
            for (int ni = 0; ni < NI; ++ni) {
                int R = wc * (BN / 2) + ni * 16 + l15;
                bfv[ni] = *(const bf16x8*)&Blds[cur][R * 64 + (((s * 4 + lk) ^ (R & 7)) << 3)];
            }
            #pragma unroll
            for (int mi = 0; mi < MI; ++mi)
                #pragma unroll
                for (int ni = 0; ni < NI; ++ni)
                    acc[mi][ni] = __builtin_amdgcn_mfma_f32_16x16x32_bf16(af[mi], bfv[ni], acc[mi][ni], 0, 0, 0);
        }
        __syncthreads();
        cur ^= 1;
    }

    #pragma unroll
    for (int mi = 0; mi < MI; ++mi) {
        int row0 = bm + wr * (BM / 2) + mi * 16 + lk * 4;
        #pragma unroll
        for (int ni = 0; ni < NI; ++ni) {
            int col = bn + wc * (BN / 2) + ni * 16 + l15;
            float bv = BIAS ? bias[col] : 0.0f;
            #pragma unroll
            for (int rr = 0; rr < 4; ++rr) {
                int row = row0 + rr;
                float v = acc[mi][ni][rr] + bv;
                if (GELU) {
                    float xg = v;
                    v = 0.5f * xg * (1.0f + tanhf(0.7978845608028654f * (xg + 0.044715f * xg * xg * xg)));
                }
                if (RES) v += res[(size_t)row * N + col];
                if (OUTBF) ((u16*)Cout)[(size_t)row * N + col] = f2bf(v);
                else       ((float*)Cout)[(size_t)row * N + col] = v;
            }
        }
    }
}

// ---------------- MFMA flash attention (all q-tiles of a (b,h) share an XCD) ----------------
__device__ __forceinline__ float bcast_q(float f0, float f1, float f2, float f3, int l15) {
    int src = (l15 >> 2) * 16;
    float a = __shfl(f0, src, 64);
    float b = __shfl(f1, src, 64);
    float c = __shfl(f2, src, 64);
    float d = __shfl(f3, src, 64);
    int r = l15 & 3;
    return r == 0 ? a : (r == 1 ? b : (r == 2 ? c : d));
}

__global__ __launch_bounds__(256) void attn_mfma(const u16* __restrict__ qkv, u16* __restrict__ ctx) {
    int id = blockIdx.x;
    int slot = id & 7, r0_ = id >> 3;
    int qt = r0_ & 7;
    int bh = (r0_ >> 3) * 8 + slot;
    int b = bh / NHEAD, h = bh % NHEAD;
    int tid = threadIdx.x;
    int w = tid >> 6, lane = tid & 63;
    int l15 = lane & 15, lk = lane >> 4;

    __shared__ u16 Klds[64][72];
    __shared__ u16 Vt[64][72];
    __shared__ u16 Plds[4][16][72];

    int q0 = qt * 64;
    const u16* qbase = qkv + (size_t)(b * SEQ + q0 + w * 16 + l15) * 2304 + h * HDIM;
    bf16x8 qf0 = *(const bf16x8*)(qbase + lk * 8);
    bf16x8 qf1 = *(const bf16x8*)(qbase + 32 + lk * 8);

    f32x4 acc_o[4];
    #pragma unroll
    for (int i = 0; i < 4; ++i) { f32x4 z = {0.f,0.f,0.f,0.f}; acc_o[i] = z; }
    float m_run[4] = {-INFINITY, -INFINITY, -INFINITY, -INFINITY};
    float l_run[4] = {0.f, 0.f, 0.f, 0.f};

    int srow = tid >> 2, sc = (tid & 3) * 16;
    int vcol = srow ^ ((sc >> 4) << 4);
    const u16* kg = qkv + (size_t)(b * SEQ) * 2304 + 768  + h * HDIM;
    const u16* vg = qkv + (size_t)(b * SEQ) * 2304 + 1536 + h * HDIM;

    for (int kt = qt; kt < SEQ / 64; ++kt) {
        int kk0 = kt * 64;
        const u16* kp = kg + (size_t)(kk0 + srow) * 2304 + sc;
        const u16* vp = vg + (size_t)(kk0 + srow) * 2304 + sc;
        uint4 kv0 = *(const uint4*)kp, kv1 = *(const uint4*)(kp + 8);
        uint4 vv0 = *(const uint4*)vp, vv1 = *(const uint4*)(vp + 8);
        __syncthreads();
        *(uint4*)&Klds[srow][sc]     = kv0;
        *(uint4*)&Klds[srow][sc + 8] = kv1;
        {
            const u16* vs = (const u16*)&vv0;
            #pragma unroll
            for (int i = 0; i < 8; ++i) Vt[sc + i][vcol] = vs[i];
            const u16* vs1 = (const u16*)&vv1;
            #pragma unroll
            for (int i = 0; i < 8; ++i) Vt[sc + 8 + i][vcol] = vs1[i];
        }
        __syncthreads();

        f32x4 accs[4];
        #pragma unroll
        for (int kb = 0; kb < 4; ++kb) { f32x4 z = {0.f,0.f,0.f,0.f}; accs[kb] = z; }
        __builtin_amdgcn_s_setprio(1);
        #pragma unroll
        for (int kb = 0; kb < 4; ++kb) {
            bf16x8 kf0 = *(const bf16x8*)&Klds[kb * 16 + l15][lk * 8];
            bf16x8 kf1 = *(const bf16x8*)&Klds[kb * 16 + l15][32 + lk * 8];
            accs[kb] = __builtin_amdgcn_mfma_f32_16x16x32_bf16(qf0, kf0, accs[kb], 0, 0, 0);
            accs[kb] = __builtin_amdgcn_mfma_f32_16x16x32_bf16(qf1, kf1, accs[kb], 0, 0, 0);
        }
        __builtin_amdgcn_s_setprio(0);

        bool diag = (kt == qt);
        float s[4][4];
        #pragma unroll
        for (int kb = 0; kb < 4; ++kb)
            #pragma unroll
            for (int r = 0; r < 4; ++r) {
                float v = accs[kb][r] * 0.125f;
                if (diag && (kk0 + kb * 16 + l15) < (q0 + w * 16 + lk * 4 + r)) v = -INFINITY;
                s[kb][r] = v;
            }
        float fac[4];
        #pragma unroll
        for (int r = 0; r < 4; ++r) {
            float mx = fmaxf(fmaxf(s[0][r], s[1][r]), fmaxf(s[2][r], s[3][r]));
            #pragma unroll
            for (int o = 8; o >= 1; o >>= 1) mx = fmaxf(mx, __shfl_xor(mx, o, 64));
            float mn = fmaxf(m_run[r], mx);
            fac[r] = expf(m_run[r] - mn);
            m_run[r] = mn;
        }
        u16 pb[4][4];
        #pragma unroll
        for (int r = 0; r < 4; ++r) {
            float rs = 0.f;
            #pragma unroll
            for (int kb = 0; kb < 4; ++kb) {
                float p = expf(s[kb][r] - m_run[r]);
                pb[kb][r] = f2bf(p);
                rs += p;
            }
            #pragma unroll
            for (int o = 8; o >= 1; o >>= 1) rs += __shfl_xor(rs, o, 64);
            l_run[r] = l_run[r] * fac[r] + rs;
        }
        #pragma unroll
        for (int kb = 0; kb < 4; ++kb)
            #pragma unroll
            for (int r = 0; r < 4; ++r)
                Plds[w][lk * 4 + r][kb * 16 + l15] = pb[kb][r];
        float fq = bcast_q(fac[0], fac[1], fac[2], fac[3], l15);
        #pragma unroll
        for (int db = 0; db < 4; ++db)
            #pragma unroll
            for (int r = 0; r < 4; ++r) acc_o[db][r] *= fq;
        __syncthreads();

        __builtin_amdgcn_s_setprio(1);
        #pragma unroll
        for (int ks = 0; ks < 2; ++ks) {
            bf16x8 pf = *(const bf16x8*)&Plds[w][l15][ks * 32 + lk * 8];
            #pragma unroll
            for (int db = 0; db < 4; ++db) {
                bf16x8 vf = *(const bf16x8*)&Vt[db * 16 + l15][(ks * 32 + lk * 8) ^ (db << 4)];
                acc_o[db] = __builtin_amdgcn_mfma_f32_16x16x32_bf16(vf, pf, acc_o[db], 0, 0, 0);
            }
        }
        __builtin_amdgcn_s_setprio(0);
    }

    float invq;
    {
        float i0 = 1.0f / l_run[0], i1 = 1.0f / l_run[1], i2 = 1.0f / l_run[2], i3 = 1.0f / l_run[3];
        invq = bcast_q(i0, i1, i2, i3, l15);
    }
    u16* cp = ctx + (size_t)(b * SEQ + q0 + w * 16 + l15) * DMODEL + h * HDIM;
    #pragma unroll
    for (int db = 0; db < 4; ++db) {
        ushort4 st;
        st.x = f2bf(acc_o[db][0] * invq);
        st.y = f2bf(acc_o[db][1] * invq);
        st.z = f2bf(acc_o[db][2] * invq);
        st.w = f2bf(acc_o[db][3] * invq);
        *(ushort4*)(cp + db * 16 + lk * 4) = st;
    }
}

// ================= fp32 fallback (round-0 proven path, used if ws too small) =================
template<bool BIAS, bool RES, bool GELU>
__global__ __launch_bounds__(256) void gemm_f32(const float* __restrict__ A, const float* __restrict__ W,
                                                const float* __restrict__ bias, const float* __restrict__ res,
                                                float* __restrict__ C, int M, int N, int K) {
    const int BM = 64, BN = 64, BK = 16;
    __shared__ float sA[BK][BM + 4];
    __shared__ float sB[BK][BN + 4];
    int tid = threadIdx.x;
    int tx = tid & 15, ty = tid >> 4;
    int bm = blockIdx.y * BM, bn = blockIdx.x * BN;
    float acc[4][4] = {};
    const float* Ab = A + (size_t)bm * K;
    const float* Wb = W + bn;
    for (int k0 = 0; k0 < K; k0 += BK) {
        {
            int rr = tid >> 2, c = (tid & 3) * 4;
            float4 va = *(const float4*)(Ab + (size_t)rr * K + k0 + c);
            sA[c + 0][rr] = va.x; sA[c + 1][rr] = va.y; sA[c + 2][rr] = va.z; sA[c + 3][rr] = va.w;
        }
        {
            int rr = tid >> 4, c = (tid & 15) * 4;
            float4 vb = *(const float4*)(Wb + (size_t)(k0 + rr) * N + c);
            *(float4*)(&sB[rr][c]) = vb;
        }
        __syncthreads();
        #pragma unroll
        for (int kk = 0; kk < BK; ++kk) {
            float4 a4 = *(const float4*)(&sA[kk][ty * 4]);
            float4 b4 = *(const float4*)(&sB[kk][tx * 4]);
            float a[4] = {a4.x, a4.y, a4.z, a4.w};
            float b[4] = {b4.x, b4.y, b4.z, b4.w};
            #pragma unroll
            for (int i = 0; i < 4; ++i)
                #pragma unroll
                for (int j = 0; j < 4; ++j) acc[i][j] += a[i] * b[j];
        }
        __syncthreads();
    }
    #pragma unroll
    for (int i = 0; i < 4; ++i) {
        int row = bm + ty * 4 + i;
        #pragma unroll
        for (int j = 0; j < 4; ++j) {
            int col = bn + tx * 4 + j;
            float v = acc[i][j];
            if (BIAS) v += bias[col];
            if (GELU) { float xg = v; v = 0.5f * xg * (1.0f + tanhf(0.7978845608028654f * (xg + 0.044715f * xg * xg * xg))); }
            if (RES) v += res[(size_t)row * N + col];
            C[(size_t)row * N + col] = v;
        }
    }
}

__global__ __launch_bounds__(256) void attn_f32(const float* __restrict__ q, const float* __restrict__ k,
                                                const float* __restrict__ v, float* __restrict__ ctx) {
    int blk = blockIdx.x;
    int qi = blk & (SEQ - 1);
    int tmp = blk >> 9;
    int h = tmp % NHEAD;
    int b = tmp / NHEAD;
    int tid = threadIdx.x;
    __shared__ float qv[HDIM];
    __shared__ float p[SEQ];
    __shared__ float rmax[4];
    __shared__ float rsum[4];
    __shared__ float part[4][HDIM];
    const float* qptr = q + ((size_t)(b * SEQ + qi) * DMODEL + h * HDIM);
    if (tid < HDIM) qv[tid] = qptr[tid];
    __syncthreads();
    float sc[2];
    #pragma unroll
    for (int c = 0; c < 2; ++c) {
        int kk = tid + c * 256;
        const float* kptr = k + ((size_t)(b * SEQ + kk) * DMODEL + h * HDIM);
        float dot = 0.0f;
        #pragma unroll
        for (int d = 0; d < HDIM; ++d) dot += qv[d] * kptr[d];
        sc[c] = (kk >= qi) ? dot * 0.125f : -INFINITY;
    }
    int wid = tid >> 6, lane = tid & 63;
    float m = fmaxf(sc[0], sc[1]);
    for (int o = 32; o > 0; o >>= 1) m = fmaxf(m, __shfl_down(m, o));
    if (lane == 0) rmax[wid] = m;
    __syncthreads();
    m = fmaxf(fmaxf(rmax[0], rmax[1]), fmaxf(rmax[2], rmax[3]));
    float e0 = expf(sc[0] - m);
    float e1 = expf(sc[1] - m);
    p[tid] = e0; p[tid + 256] = e1;
    float sum = e0 + e1;
    for (int o = 32; o > 0; o >>= 1) sum += __shfl_down(sum, o);
    if (lane == 0) rsum[wid] = sum;
    __syncthreads();
    float inv = 1.0f / (rsum[0] + rsum[1] + rsum[2] + rsum[3]);
    int d = tid & 63, ch = tid >> 6;
    float accv = 0.0f;
    const float* vbase = v + ((size_t)b * SEQ * DMODEL + h * HDIM + d);
    for (int kk = ch * 128; kk < (ch + 1) * 128; ++kk) accv += p[kk] * vbase[(size_t)kk * DMODEL];
    part[ch][d] = accv;
    __syncthreads();
    if (tid < HDIM) {
        float rv = (part[0][tid] + part[1][tid] + part[2][tid] + part[3][tid]) * inv;
        ctx[((size_t)(b * SEQ + qi) * DMODEL + h * HDIM + tid)] = rv;
    }
}

extern "C" void kernel_launch(void* const* d_in, const int* in_sizes, int n_in,
                              void* d_out, int out_size, void* d_ws, size_t ws_size,
                              hipStream_t stream) {
    const int*   x   = (const int*)d_in[0];
    const float* tok = (const float*)d_in[1];
    const float* pos = (const float*)d_in[2];
    const float* n1s = (const float*)d_in[3];
    const float* n1b = (const float*)d_in[4];
    const float* n2s = (const float*)d_in[5];
    const float* n2b = (const float*)d_in[6];
    const float* wq  = (const float*)d_in[7];
    const float* wk  = (const float*)d_in[8];
    const float* wv  = (const float*)d_in[9];
    const float* wo  = (const float*)d_in[10];
    const float* bo  = (const float*)d_in[11];
    const float* w1  = (const float*)d_in[12];
    const float* b1  = (const float*)d_in[13];
    const float* w2  = (const float*)d_in[14];
    const float* b2  = (const float*)d_in[15];
    const float* fs  = (const float*)d_in[16];
    const float* fb  = (const float*)d_in[17];
    const float* hw  = (const float*)d_in[18];
    const float* hb  = (const float*)d_in[19];
    float* out = (float*)d_out;

    const size_t szWtQKV = (size_t)NLAYER * 2304 * 768 * 2;
    const size_t szWtO   = (size_t)NLAYER * 768 * 768 * 2;
    const size_t szWt1   = (size_t)NLAYER * 3072 * 768 * 2;
    const size_t szWt2   = (size_t)NLAYER * 768 * 3072 * 2;
    const size_t szWtH   = (size_t)VOCAB * 768 * 2;
    const size_t szH     = (size_t)MROWS * DMODEL * 4;
    const size_t szHN    = (size_t)MROWS * DMODEL * 2;
    const size_t szQKV   = (size_t)MROWS * 2304 * 2;
    const size_t szCTX   = (size_t)MROWS * DMODEL * 2;
    const size_t szFF    = (size_t)MROWS * 3072 * 2;
    const size_t NEED = szWtQKV + szWtO + szWt1 + szWt2 + szWtH + szH + szHN + szQKV + szCTX + szFF;

    if (ws_size >= NEED) {
        char* p = (char*)d_ws;
        u16* WtQKV = (u16*)p; p += szWtQKV;
        u16* WtO   = (u16*)p; p += szWtO;
        u16* Wt1   = (u16*)p; p += szWt1;
        u16* Wt2   = (u16*)p; p += szWt2;
        u16* WtH   = (u16*)p; p += szWtH;
        float* h   = (float*)p; p += szH;
        u16* hn    = (u16*)p; p += szHN;
        u16* qkv   = (u16*)p; p += szQKV;
        u16* ctx   = (u16*)p; p += szCTX;
        u16* ff    = (u16*)p; p += szFF;

        transpose_qkvo<<<dim3(12, 12, 24), 256, 0, stream>>>(wq, wk, wv, wo, WtQKV, WtO);
        transpose_conv<<<dim3(48, 12, NLAYER), 256, 0, stream>>>(w1, Wt1, 768, 3072, 768 * 3072, 3072 * 768);
        transpose_conv<<<dim3(12, 48, NLAYER), 256, 0, stream>>>(w2, Wt2, 3072, 768, 3072 * 768, 768 * 3072);
        transpose_conv<<<dim3(500, 12, 1), 256, 0, stream>>>(hw, WtH, 768, VOCAB, 0, 0);

        embed_kernel<<<(MROWS * DMODEL + 255) / 256, 256, 0, stream>>>(x, tok, pos, h);

        for (int l = 0; l < NLAYER; ++l) {
            const u16* wtqkv = WtQKV + (size_t)l * 2304 * 768;
            const u16* wto   = WtO   + (size_t)l * 768 * 768;
            const u16* wt1   = Wt1   + (size_t)l * 3072 * 768;
            const u16* wt2   = Wt2   + (size_t)l * 768 * 3072;

            norm_kernel<true><<<MROWS, 256, 0, stream>>>(h, n1s + l * DMODEL, n1b + l * DMODEL, hn);
            gemm_sm<true,false,false,false,64,64><<<576, 256, 0, stream>>>(hn, wtqkv, nullptr, nullptr, qkv, MROWS, 2304, 768);
            attn_mfma<<<192, 256, 0, stream>>>(qkv, ctx);
            gemm_sm<false,true,true,false,32,64><<<384, 256, 0, stream>>>(ctx, wto, bo + l * DMODEL, h, h, MROWS, 768, 768);
            norm_kernel<true><<<MROWS, 256, 0, stream>>>(h, n2s + l * DMODEL, n2b + l * DMODEL, hn);
            gemm_sm<true,true,false,true,64,64><<<768, 256, 0, stream>>>(hn, wt1, b1 + (size_t)l * 3072, nullptr, ff, MROWS, 3072, 768);
            gemm_sm<false,true,true,false,32,64><<<384, 256, 0, stream>>>(ff, wt2, b2 + l * DMODEL, h, h, MROWS, 768, 3072);
        }
        norm_kernel<true><<<MROWS, 256, 0, stream>>>(h, fs, fb, hn);
        gemm_hd<<<2000, 256, 0, stream>>>(hn, WtH, hb, out, MROWS, VOCAB, 768);
        return;
    }

    // ---------- fp32 fallback ----------
    float* ws  = (float*)d_ws;
    float* h   = ws;
    float* hnf = h   + (size_t)MROWS * DMODEL;
    float* qb  = hnf + (size_t)MROWS * DMODEL;
    float* kb  = qb  + (size_t)MROWS * DMODEL;
    float* vb  = kb  + (size_t)MROWS * DMODEL;
    float* ctxf= vb  + (size_t)MROWS * DMODEL;
    float* fff = ctxf+ (size_t)MROWS * DMODEL;

    embed_kernel<<<(MROWS * DMODEL + 255) / 256, 256, 0, stream>>>(x, tok, pos, h);
    dim3 g768(DMODEL / 64, MROWS / 64);
    dim3 g3072(4 * DMODEL / 64, MROWS / 64);
    dim3 gV(VOCAB / 64, MROWS / 64);
    for (int l = 0; l < NLAYER; ++l) {
        size_t wOff  = (size_t)l * DMODEL * DMODEL;
        size_t w1Off = (size_t)l * DMODEL * 4 * DMODEL;
        norm_kernel<false><<<MROWS, 256, 0, stream>>>(h, n1s + l * DMODEL, n1b + l * DMODEL, hnf);
        gemm_f32<false,false,false><<<g768, 256, 0, stream>>>(hnf, wq + wOff, nullptr, nullptr, qb, MROWS, DMODEL, DMODEL);
        gemm_f32<false,false,false><<<g768, 256, 0, stream>>>(hnf, wk + wOff, nullptr, nullptr, kb, MROWS, DMODEL, DMODEL);
        gemm_f32<false,false,false><<<g768, 256, 0, stream>>>(hnf, wv + wOff, nullptr, nullptr, vb, MROWS, DMODEL, DMODEL);
        attn_f32<<<BDIM * NHEAD * SEQ, 256, 0, stream>>>(qb, kb, vb, ctxf);
        gemm_f32<true,true,false><<<g768, 256, 0, stream>>>(ctxf, wo + wOff, bo + l * DMODEL, h, h, MROWS, DMODEL, DMODEL);
        norm_kernel<false><<<MROWS, 256, 0, stream>>>(h, n2s + l * DMODEL, n2b + l * DMODEL, hnf);
        gemm_f32<true,false,true><<<g3072, 256, 0, stream>>>(hnf, w1 + w1Off, b1 + (size_t)l * 4 * DMODEL, nullptr, fff, MROWS, 4 * DMODEL, DMODEL);
        gemm_f32<true,true,false><<<g768, 256, 0, stream>>>(fff, w2 + w1Off, b2 + l * DMODEL, h, h, MROWS, DMODEL, 4 * DMODEL);
    }
    norm_kernel<false><<<MROWS, 256, 0, stream>>>(h, fs, fb, hnf);
    gemm_f32<true,false,false><<<gV, 256, 0, stream>>>(hnf, hw, hb, nullptr, out, MROWS, VOCAB, DMODEL);
}

// Round 17
// 788.565 us; speedup vs baseline: 1.0074x; 1.0074x over previous
//
#include <hip/hip_runtime.h>
#include <math.h>

#define BDIM 2
#define SEQ 512
#define DMODEL 768
#define NHEAD 12
#define HDIM 64
#define NLAYER 6
#define VOCAB 32000
#define MROWS (BDIM*SEQ)   // 1024
#define EPSV 1e-6f

typedef unsigned short u16;
typedef unsigned int u32;
typedef __bf16 bf16x8 __attribute__((ext_vector_type(8)));
typedef float f32x4 __attribute__((ext_vector_type(4)));

__device__ __forceinline__ u16 f2bf(float f) {
    union { float f; u32 u; } v; v.f = f;
    u32 r = v.u + 0x7fffu + ((v.u >> 16) & 1u);   // RNE
    return (u16)(r >> 16);
}
__device__ __forceinline__ float bf2f(u16 b) {
    union { u32 u; float f; } v; v.u = ((u32)b) << 16;
    return v.f;
}

// async global->LDS, 16B per lane, dest = wave-uniform base + lane*16
__device__ __forceinline__ void gload16(const u16* g, u16* l) {
    __builtin_amdgcn_global_load_lds(
        (const __attribute__((address_space(1))) unsigned int*)g,
        (__attribute__((address_space(3))) unsigned int*)l,
        16, 0, 0);
}

// ---------------- embedding (h stays fp32) ----------------
__global__ void embed_kernel(const int* __restrict__ x, const float* __restrict__ tok,
                             const float* __restrict__ pos, float* __restrict__ h) {
    int i = blockIdx.x * blockDim.x + threadIdx.x;
    if (i >= MROWS * DMODEL) return;
    int bs = i / DMODEL, d = i - bs * DMODEL;
    int s = bs & (SEQ - 1);
    h[i] = tok[(size_t)x[bs] * DMODEL + d] + pos[(size_t)s * DMODEL + d];
}

// ---------------- transpose + fp32->bf16: in[K][N] -> out[N][K], 64x64 tiles, vec IO ----------------
__global__ __launch_bounds__(256) void transpose_conv(const float* __restrict__ in, u16* __restrict__ out,
                                                      int K, int N, long in_bs, long out_bs) {
    __shared__ float t[64][65];
    int b = blockIdx.z;
    int n0 = blockIdx.x * 64, k0 = blockIdx.y * 64;
    int tid = threadIdx.x;
    const float* ip = in + (size_t)b * in_bs;
    int kr = tid >> 4, nc = (tid & 15) * 4;
    #pragma unroll
    for (int i = 0; i < 4; ++i) {
        float4 v = *(const float4*)(ip + (size_t)(k0 + kr + i * 16) * N + n0 + nc);
        t[kr + i * 16][nc] = v.x; t[kr + i * 16][nc + 1] = v.y;
        t[kr + i * 16][nc + 2] = v.z; t[kr + i * 16][nc + 3] = v.w;
    }
    __syncthreads();
    u16* op = out + (size_t)b * out_bs;
    int nr = tid >> 4, kc = (tid & 15) * 4;
    #pragma unroll
    for (int i = 0; i < 4; ++i) {
        ushort4 s;
        s.x = f2bf(t[kc + 0][nr + i * 16]);
        s.y = f2bf(t[kc + 1][nr + i * 16]);
        s.z = f2bf(t[kc + 2][nr + i * 16]);
        s.w = f2bf(t[kc + 3][nr + i * 16]);
        *(ushort4*)(op + (size_t)(n0 + nr + i * 16) * K + k0 + kc) = s;
    }
}

// merged transpose for the 4 square 768x768 weight families (z = layer*4 + which)
__global__ __launch_bounds__(256) void transpose_qkvo(const float* __restrict__ wq, const float* __restrict__ wk,
                                                      const float* __restrict__ wv, const float* __restrict__ wo,
                                                      u16* __restrict__ WtQKV, u16* __restrict__ WtO) {
    __shared__ float t[64][65];
    int z = blockIdx.z;
    int which = z & 3, l = z >> 2;
    const float* srcs[4] = {wq, wk, wv, wo};
    const float* ip = srcs[which] + (size_t)l * 768 * 768;
    u16* op = (which < 3) ? (WtQKV + (size_t)l * 2304 * 768 + (size_t)which * 768 * 768)
                          : (WtO + (size_t)l * 768 * 768);
    int n0 = blockIdx.x * 64, k0 = blockIdx.y * 64;
    int tid = threadIdx.x;
    int kr = tid >> 4, nc = (tid & 15) * 4;
    #pragma unroll
    for (int i = 0; i < 4; ++i) {
        float4 v = *(const float4*)(ip + (size_t)(k0 + kr + i * 16) * 768 + n0 + nc);
        t[kr + i * 16][nc] = v.x; t[kr + i * 16][nc + 1] = v.y;
        t[kr + i * 16][nc + 2] = v.z; t[kr + i * 16][nc + 3] = v.w;
    }
    __syncthreads();
    int nr = tid >> 4, kc = (tid & 15) * 4;
    #pragma unroll
    for (int i = 0; i < 4; ++i) {
        ushort4 s;
        s.x = f2bf(t[kc + 0][nr + i * 16]);
        s.y = f2bf(t[kc + 1][nr + i * 16]);
        s.z = f2bf(t[kc + 2][nr + i * 16]);
        s.w = f2bf(t[kc + 3][nr + i * 16]);
        *(ushort4*)(op + (size_t)(n0 + nr + i * 16) * 768 + k0 + kc) = s;
    }
}

// ---------------- DummyNorm: s*(x-mean)/(std_ddof1 + eps) + b ----------------
template<bool OUTBF>
__global__ __launch_bounds__(256) void norm_kernel(const float* __restrict__ in,
                                                   const float* __restrict__ scale,
                                                   const float* __restrict__ bias,
                                                   void* __restrict__ outp) {
    int row = blockIdx.x;
    const float* xr = in + (size_t)row * DMODEL;
    int t = threadIdx.x;
    float v0 = xr[t], v1 = xr[t + 256], v2 = xr[t + 512];

    float s = v0 + v1 + v2;
    for (int o = 32; o > 0; o >>= 1) s += __shfl_down(s, o);
    __shared__ float red1[4];
    __shared__ float red2[4];
    int wid = t >> 6, lane = t & 63;
    if (lane == 0) red1[wid] = s;
    __syncthreads();
    float mean = (red1[0] + red1[1] + red1[2] + red1[3]) * (1.0f / DMODEL);

    float d0 = v0 - mean, d1 = v1 - mean, d2 = v2 - mean;
    float ss = d0 * d0 + d1 * d1 + d2 * d2;
    for (int o = 32; o > 0; o >>= 1) ss += __shfl_xor(ss, o);
    if (lane == 0) red2[wid] = ss;
    __syncthreads();
    float var = (red2[0] + red2[1] + red2[2] + red2[3]) * (1.0f / (DMODEL - 1));
    float inv = 1.0f / (sqrtf(var) + EPSV);

    size_t o0 = (size_t)row * DMODEL + t;
    float r0 = scale[t] * d0 * inv + bias[t];
    float r1 = scale[t + 256] * d1 * inv + bias[t + 256];
    float r2 = scale[t + 512] * d2 * inv + bias[t + 512];
    if (OUTBF) {
        u16* out = (u16*)outp;
        out[o0] = f2bf(r0); out[o0 + 256] = f2bf(r1); out[o0 + 512] = f2bf(r2);
    } else {
        float* out = (float*)outp;
        out[o0] = r0; out[o0 + 256] = r1; out[o0 + 512] = r2;
    }
}

// ======================= bf16 MFMA GEMMs, global_load_lds + dbuf + XOR swizzle ==================

// ---------------- 128x128 head GEMM, BK=32 (LDS 32KB -> 5 blocks/CU) ----------------
// Super-row layout: storage = 64 super-rows of 128B (2 logical rows each). Element (R,k):
//   byte = (R>>1)*128 + ((((R&1)<<2) + (k>>3)) ^ ((R>>1)&7))*16 + (k&7)*2
// Staging: one linear gload16 per 16 rows; per-lane global source permutation is FIXED:
//   q=(l&7)^(l>>3); R_l=2*(l>>3)+(q>>2); c_l=q&3. Reads: 8 distinct 16B slots x2 lanes = 2-way (free).
__global__ __launch_bounds__(256) void gemm_hd(const u16* __restrict__ A,
                                               const u16* __restrict__ Wt,
                                               const float* __restrict__ bias,
                                               float* __restrict__ Cout,
                                               int M, int N, int K) {
    __shared__ u16 Alds[2][128 * 32];
    __shared__ u16 Blds[2][128 * 32];
    int tid = threadIdx.x;
    int lane = tid & 63;
    int wid = tid >> 6;
    int l15 = lane & 15, lk = lane >> 4;
    int wm = (wid >> 1) * 64, wn = (wid & 1) * 64;
    // XCD panel swizzle (grid 2000, %8==0)
    int id = blockIdx.x;
    int xcd = id & 7, jj = id >> 3;
    int g = xcd * ((int)gridDim.x >> 3) + jj;
    int mb = M >> 7;
    int bn = (g / mb) * 128;
    int bm = (g % mb) * 128;

    f32x4 acc[4][4];
    #pragma unroll
    for (int i = 0; i < 4; ++i)
        #pragma unroll
        for (int j = 0; j < 4; ++j) { f32x4 z = {0.f, 0.f, 0.f, 0.f}; acc[i][j] = z; }

    // fixed per-lane staging source
    int q  = (lane & 7) ^ (lane >> 3);
    int Rl = 2 * (lane >> 3) + (q >> 2);
    int cl = q & 3;
    const u16* gA = A  + (size_t)(bm + Rl) * K + cl * 8;
    const u16* gB = Wt + (size_t)(bn + Rl) * K + cl * 8;

    auto STAGE = [&](int buf, int k0) {
        #pragma unroll
        for (int i = 0; i < 2; ++i) {
            int rb = (wid * 2 + i) * 16;      // 16-row region
            gload16(gA + (size_t)rb * K + k0, &Alds[buf][rb * 32]);
            gload16(gB + (size_t)rb * K + k0, &Blds[buf][rb * 32]);
        }
    };

    STAGE(0, 0);
    __syncthreads();
    int nt = K >> 5;
    int cur = 0;
    for (int t = 0; t < nt; ++t) {
        if (t + 1 < nt) STAGE(cur ^ 1, (t + 1) << 5);

        bf16x8 af[4], bfv[4];
        #pragma unroll
        for (int mi = 0; mi < 4; ++mi) {
            int R = wm + mi * 16 + l15;
            int ci = ((((R & 1) << 2) + lk) ^ ((R >> 1) & 7));
            af[mi] = *(const bf16x8*)&Alds[cur][(R >> 1) * 64 + ci * 8];
        }
        #pragma unroll
        for (int ni = 0; ni < 4; ++ni) {
            int R = wn + ni * 16 + l15;
            int ci = ((((R & 1) << 2) + lk) ^ ((R >> 1) & 7));
            bfv[ni] = *(const bf16x8*)&Blds[cur][(R >> 1) * 64 + ci * 8];
        }
        #pragma unroll
        for (int mi = 0; mi < 4; ++mi)
            #pragma unroll
            for (int ni = 0; ni < 4; ++ni)
                acc[mi][ni] = __builtin_amdgcn_mfma_f32_16x16x32_bf16(af[mi], bfv[ni], acc[mi][ni], 0, 0, 0);

        __syncthreads();   // drains vmcnt(0): next tile landed; cur free to overwrite
        cur ^= 1;
    }

    #pragma unroll
    for (int mi = 0; mi < 4; ++mi) {
        int row0 = bm + wm + mi * 16 + lk * 4;
        #pragma unroll
        for (int ni = 0; ni < 4; ++ni) {
            int col = bn + wn + ni * 16 + l15;
            float bv = bias[col];
            #pragma unroll
            for (int rr = 0; rr < 4; ++rr) {
                int row = row0 + rr;
                Cout[(size_t)row * N + col] = acc[mi][ni][rr] + bv;
            }
        }
    }
}

// ---------------- BMxBN layer GEMMs, BK=64, 1-D grid + XCD panel-grouping swizzle ----------------
// LDS tiles LINEAR [rows][64] bf16. 16B chunk c8 of row r lives at chunk c8^(r&7) (involution,
// applied to the per-lane GLOBAL SOURCE at stage time and to the ds_read addr at use time).
template<bool OUTBF, bool BIAS, bool RES, bool GELU, int BM, int BN>
__global__ __launch_bounds__(256) void gemm_sm(const u16* __restrict__ A,
                                               const u16* __restrict__ Wt,
                                               const float* __restrict__ bias,
                                               const float* __restrict__ res,
                                               void* __restrict__ Cout,
                                               int M, int N, int K) {
    __shared__ u16 Alds[2][BM * 64];
    __shared__ u16 Blds[2][BN * 64];
    int tid = threadIdx.x;
    int lane = tid & 63;
    int wid = tid >> 6;
    int l15 = lane & 15, lk = lane >> 4;
    int wr = wid >> 1, wc = wid & 1;           // 2x2 waves; wave tile (BM/2)x(BN/2)
    int id = blockIdx.x;
    int xcd = id & 7, j = id >> 3;
    int g = xcd * ((int)gridDim.x >> 3) + j;
    int mb = M / BM;
    int bn = (g / mb) * BN;
    int bm = (g % mb) * BM;
    constexpr int MI = BM / 32;
    constexpr int NI = BN / 32;

    f32x4 acc[MI][NI];
    #pragma unroll
    for (int i = 0; i < MI; ++i)
        #pragma unroll
        for (int j2 = 0; j2 < NI; ++j2) { f32x4 z = {0.f, 0.f, 0.f, 0.f}; acc[i][j2] = z; }

    int lr  = lane >> 3;
    int lc8 = (lane & 7) ^ lr;
    const u16* gA = A  + (size_t)(bm + lr) * K + lc8 * 8;
    const u16* gB = Wt + (size_t)(bn + lr) * K + lc8 * 8;

    auto STAGE = [&](int buf, int k0) {
        #pragma unroll
        for (int i = 0; i < MI; ++i) {
            int rb = wid * (BM / 4) + i * 8;
            gload16(gA + (size_t)rb * K + k0, &Alds[buf][rb * 64]);
        }
        #pragma unroll
        for (int i = 0; i < NI; ++i) {
            int rb = wid * (BN / 4) + i * 8;
            gload16(gB + (size_t)rb * K + k0, &Blds[buf][rb * 64]);
        }
    };

    STAGE(0, 0);
    __syncthreads();
    int nt = K >> 6;
    int cur = 0;
    for (int t = 0; t < nt; ++t) {
        if (t + 1 < nt) STAGE(cur ^ 1, (t + 1) << 6);

        #pragma unroll
        for (int s = 0; s < 2; ++s) {
            bf16x8 af[MI], bfv[NI];
            #pragma unroll
            for (int mi = 0; mi < MI; ++mi) {
                int R = wr * (BM / 2) + mi * 16 + l15;
                af[mi] = *(const bf16x8*)&Alds[cur][R * 64 + (((s * 4 + lk) ^ (R & 7)) << 3)];
            }
            #pragma unroll
            for (int ni = 0; ni < NI; ++ni) {
                int R = wc * (BN / 2) + ni * 16 + l15;
                bfv[ni] = *(const bf16x8*)&Blds[cur][R * 64 + (((s * 4 + lk) ^ (R & 7)) << 3)];
            }
            #pragma unroll
            for (int mi = 0; mi < MI; ++mi)
                #pragma unroll
                for (int ni = 0; ni < NI; ++ni)
                    acc[mi][ni] = __builtin_amdgcn_mfma_f32_16x16x32_bf16(af[mi], bfv[ni], acc[mi][ni], 0, 0, 0);
        }
        __syncthreads();
        cur ^= 1;
    }

    #pragma unroll
    for (int mi = 0; mi < MI; ++mi) {
        int row0 = bm + wr * (BM / 2) + mi * 16 + lk * 4;
        #pragma unroll
        for (int ni = 0; ni < NI; ++ni) {
            int col = bn + wc * (BN / 2) + ni * 16 + l15;
            float bv = BIAS ? bias[col] : 0.0f;
            #pragma unroll
            for (int rr = 0; rr < 4; ++rr) {
                int row = row0 + rr;
                float v = acc[mi][ni][rr] + bv;
                if (GELU) {
                    float xg = v;
                    v = 0.5f * xg * (1.0f + tanhf(0.7978845608028654f * (xg + 0.044715f * xg * xg * xg)));
                }
                if (RES) v += res[(size_t)row * N + col];
                if (OUTBF) ((u16*)Cout)[(size_t)row * N + col] = f2bf(v);
                else       ((float*)Cout)[(size_t)row * N + col] = v;
            }
        }
    }
}

// ---------------- MFMA flash attention (all q-tiles of a (b,h) share an XCD) ----------------
__device__ __forceinline__ float bcast_q(float f0, float f1, float f2, float f3, int l15) {
    int src = (l15 >> 2) * 16;
    float a = __shfl(f0, src, 64);
    float b = __shfl(f1, src, 64);
    float c = __shfl(f2, src, 64);
    float d = __shfl(f3, src, 64);
    int r = l15 & 3;
    return r == 0 ? a : (r == 1 ? b : (r == 2 ? c : d));
}

__global__ __launch_bounds__(256) void attn_mfma(const u16* __restrict__ qkv, u16* __restrict__ ctx) {
    int id = blockIdx.x;
    int slot = id & 7, r0_ = id >> 3;
    int qt = r0_ & 7;
    int bh = (r0_ >> 3) * 8 + slot;
    int b = bh / NHEAD, h = bh % NHEAD;
    int tid = threadIdx.x;
    int w = tid >> 6, lane = tid & 63;
    int l15 = lane & 15, lk = lane >> 4;

    __shared__ u16 Klds[64][72];
    __shared__ u16 Vt[64][72];
    __shared__ u16 Plds[4][16][72];

    int q0 = qt * 64;
    const u16* qbase = qkv + (size_t)(b * SEQ + q0 + w * 16 + l15) * 2304 + h * HDIM;
    bf16x8 qf0 = *(const bf16x8*)(qbase + lk * 8);
    bf16x8 qf1 = *(const bf16x8*)(qbase + 32 + lk * 8);

    f32x4 acc_o[4];
    #pragma unroll
    for (int i = 0; i < 4; ++i) { f32x4 z = {0.f,0.f,0.f,0.f}; acc_o[i] = z; }
    float m_run[4] = {-INFINITY, -INFINITY, -INFINITY, -INFINITY};
    float l_run[4] = {0.f, 0.f, 0.f, 0.f};

    int srow = tid >> 2, sc = (tid & 3) * 16;
    int vcol = srow ^ ((sc >> 4) << 4);
    const u16* kg = qkv + (size_t)(b * SEQ) * 2304 + 768  + h * HDIM;
    const u16* vg = qkv + (size_t)(b * SEQ) * 2304 + 1536 + h * HDIM;

    for (int kt = qt; kt < SEQ / 64; ++kt) {
        int kk0 = kt * 64;
        const u16* kp = kg + (size_t)(kk0 + srow) * 2304 + sc;
        const u16* vp = vg + (size_t)(kk0 + srow) * 2304 + sc;
        uint4 kv0 = *(const uint4*)kp, kv1 = *(const uint4*)(kp + 8);
        uint4 vv0 = *(const uint4*)vp, vv1 = *(const uint4*)(vp + 8);
        __syncthreads();
        *(uint4*)&Klds[srow][sc]     = kv0;
        *(uint4*)&Klds[srow][sc + 8] = kv1;
        {
            const u16* vs = (const u16*)&vv0;
            #pragma unroll
            for (int i = 0; i < 8; ++i) Vt[sc + i][vcol] = vs[i];
            const u16* vs1 = (const u16*)&vv1;
            #pragma unroll
            for (int i = 0; i < 8; ++i) Vt[sc + 8 + i][vcol] = vs1[i];
        }
        __syncthreads();

        f32x4 accs[4];
        #pragma unroll
        for (int kb = 0; kb < 4; ++kb) { f32x4 z = {0.f,0.f,0.f,0.f}; accs[kb] = z; }
        __builtin_amdgcn_s_setprio(1);
        #pragma unroll
        for (int kb = 0; kb < 4; ++kb) {
            bf16x8 kf0 = *(const bf16x8*)&Klds[kb * 16 + l15][lk * 8];
            bf16x8 kf1 = *(const bf16x8*)&Klds[kb * 16 + l15][32 + lk * 8];
            accs[kb] = __builtin_amdgcn_mfma_f32_16x16x32_bf16(qf0, kf0, accs[kb], 0, 0, 0);
            accs[kb] = __builtin_amdgcn_mfma_f32_16x16x32_bf16(qf1, kf1, accs[kb], 0, 0, 0);
        }
        __builtin_amdgcn_s_setprio(0);

        bool diag = (kt == qt);
        float s[4][4];
        #pragma unroll
        for (int kb = 0; kb < 4; ++kb)
            #pragma unroll
            for (int r = 0; r < 4; ++r) {
                float v = accs[kb][r] * 0.125f;
                if (diag && (kk0 + kb * 16 + l15) < (q0 + w * 16 + lk * 4 + r)) v = -INFINITY;
                s[kb][r] = v;
            }
        float fac[4];
        #pragma unroll
        for (int r = 0; r < 4; ++r) {
            float mx = fmaxf(fmaxf(s[0][r], s[1][r]), fmaxf(s[2][r], s[3][r]));
            #pragma unroll
            for (int o = 8; o >= 1; o >>= 1) mx = fmaxf(mx, __shfl_xor(mx, o, 64));
            float mn = fmaxf(m_run[r], mx);
            fac[r] = expf(m_run[r] - mn);
            m_run[r] = mn;
        }
        u16 pb[4][4];
        #pragma unroll
        for (int r = 0; r < 4; ++r) {
            float rs = 0.f;
            #pragma unroll
            for (int kb = 0; kb < 4; ++kb) {
                float p = expf(s[kb][r] - m_run[r]);
                pb[kb][r] = f2bf(p);
                rs += p;
            }
            #pragma unroll
            for (int o = 8; o >= 1; o >>= 1) rs += __shfl_xor(rs, o, 64);
            l_run[r] = l_run[r] * fac[r] + rs;
        }
        #pragma unroll
        for (int kb = 0; kb < 4; ++kb)
            #pragma unroll
            for (int r = 0; r < 4; ++r)
                Plds[w][lk * 4 + r][kb * 16 + l15] = pb[kb][r];
        float fq = bcast_q(fac[0], fac[1], fac[2], fac[3], l15);
        #pragma unroll
        for (int db = 0; db < 4; ++db)
            #pragma unroll
            for (int r = 0; r < 4; ++r) acc_o[db][r] *= fq;
        __syncthreads();

        __builtin_amdgcn_s_setprio(1);
        #pragma unroll
        for (int ks = 0; ks < 2; ++ks) {
            bf16x8 pf = *(const bf16x8*)&Plds[w][l15][ks * 32 + lk * 8];
            #pragma unroll
            for (int db = 0; db < 4; ++db) {
                bf16x8 vf = *(const bf16x8*)&Vt[db * 16 + l15][(ks * 32 + lk * 8) ^ (db << 4)];
                acc_o[db] = __builtin_amdgcn_mfma_f32_16x16x32_bf16(vf, pf, acc_o[db], 0, 0, 0);
            }
        }
        __builtin_amdgcn_s_setprio(0);
    }

    float invq;
    {
        float i0 = 1.0f / l_run[0], i1 = 1.0f / l_run[1], i2 = 1.0f / l_run[2], i3 = 1.0f / l_run[3];
        invq = bcast_q(i0, i1, i2, i3, l15);
    }
    u16* cp = ctx + (size_t)(b * SEQ + q0 + w * 16 + l15) * DMODEL + h * HDIM;
    #pragma unroll
    for (int db = 0; db < 4; ++db) {
        ushort4 st;
        st.x = f2bf(acc_o[db][0] * invq);
        st.y = f2bf(acc_o[db][1] * invq);
        st.z = f2bf(acc_o[db][2] * invq);
        st.w = f2bf(acc_o[db][3] * invq);
        *(ushort4*)(cp + db * 16 + lk * 4) = st;
    }
}

// ================= fp32 fallback (round-0 proven path, used if ws too small) =================
template<bool BIAS, bool RES, bool GELU>
__global__ __launch_bounds__(256) void gemm_f32(const float* __restrict__ A, const float* __restrict__ W,
                                                const float* __restrict__ bias, const float* __restrict__ res,
                                                float* __restrict__ C, int M, int N, int K) {
    const int BM = 64, BN = 64, BK = 16;
    __shared__ float sA[BK][BM + 4];
    __shared__ float sB[BK][BN + 4];
    int tid = threadIdx.x;
    int tx = tid & 15, ty = tid >> 4;
    int bm = blockIdx.y * BM, bn = blockIdx.x * BN;
    float acc[4][4] = {};
    const float* Ab = A + (size_t)bm * K;
    const float* Wb = W + bn;
    for (int k0 = 0; k0 < K; k0 += BK) {
        {
            int rr = tid >> 2, c = (tid & 3) * 4;
            float4 va = *(const float4*)(Ab + (size_t)rr * K + k0 + c);
            sA[c + 0][rr] = va.x; sA[c + 1][rr] = va.y; sA[c + 2][rr] = va.z; sA[c + 3][rr] = va.w;
        }
        {
            int rr = tid >> 4, c = (tid & 15) * 4;
            float4 vb = *(const float4*)(Wb + (size_t)(k0 + rr) * N + c);
            *(float4*)(&sB[rr][c]) = vb;
        }
        __syncthreads();
        #pragma unroll
        for (int kk = 0; kk < BK; ++kk) {
            float4 a4 = *(const float4*)(&sA[kk][ty * 4]);
            float4 b4 = *(const float4*)(&sB[kk][tx * 4]);
            float a[4] = {a4.x, a4.y, a4.z, a4.w};
            float b[4] = {b4.x, b4.y, b4.z, b4.w};
            #pragma unroll
            for (int i = 0; i < 4; ++i)
                #pragma unroll
                for (int j = 0; j < 4; ++j) acc[i][j] += a[i] * b[j];
        }
        __syncthreads();
    }
    #pragma unroll
    for (int i = 0; i < 4; ++i) {
        int row = bm + ty * 4 + i;
        #pragma unroll
        for (int j = 0; j < 4; ++j) {
            int col = bn + tx * 4 + j;
            float v = acc[i][j];
            if (BIAS) v += bias[col];
            if (GELU) { float xg = v; v = 0.5f * xg * (1.0f + tanhf(0.7978845608028654f * (xg + 0.044715f * xg * xg * xg))); }
            if (RES) v += res[(size_t)row * N + col];
            C[(size_t)row * N + col] = v;
        }
    }
}

__global__ __launch_bounds__(256) void attn_f32(const float* __restrict__ q, const float* __restrict__ k,
                                                const float* __restrict__ v, float* __restrict__ ctx) {
    int blk = blockIdx.x;
    int qi = blk & (SEQ - 1);
    int tmp = blk >> 9;
    int h = tmp % NHEAD;
    int b = tmp / NHEAD;
    int tid = threadIdx.x;
    __shared__ float qv[HDIM];
    __shared__ float p[SEQ];
    __shared__ float rmax[4];
    __shared__ float rsum[4];
    __shared__ float part[4][HDIM];
    const float* qptr = q + ((size_t)(b * SEQ + qi) * DMODEL + h * HDIM);
    if (tid < HDIM) qv[tid] = qptr[tid];
    __syncthreads();
    float sc[2];
    #pragma unroll
    for (int c = 0; c < 2; ++c) {
        int kk = tid + c * 256;
        const float* kptr = k + ((size_t)(b * SEQ + kk) * DMODEL + h * HDIM);
        float dot = 0.0f;
        #pragma unroll
        for (int d = 0; d < HDIM; ++d) dot += qv[d] * kptr[d];
        sc[c] = (kk >= qi) ? dot * 0.125f : -INFINITY;
    }
    int wid = tid >> 6, lane = tid & 63;
    float m = fmaxf(sc[0], sc[1]);
    for (int o = 32; o > 0; o >>= 1) m = fmaxf(m, __shfl_down(m, o));
    if (lane == 0) rmax[wid] = m;
    __syncthreads();
    m = fmaxf(fmaxf(rmax[0], rmax[1]), fmaxf(rmax[2], rmax[3]));
    float e0 = expf(sc[0] - m);
    float e1 = expf(sc[1] - m);
    p[tid] = e0; p[tid + 256] = e1;
    float sum = e0 + e1;
    for (int o = 32; o > 0; o >>= 1) sum += __shfl_down(sum, o);
    if (lane == 0) rsum[wid] = sum;
    __syncthreads();
    float inv = 1.0f / (rsum[0] + rsum[1] + rsum[2] + rsum[3]);
    int d = tid & 63, ch = tid >> 6;
    float accv = 0.0f;
    const float* vbase = v + ((size_t)b * SEQ * DMODEL + h * HDIM + d);
    for (int kk = ch * 128; kk < (ch + 1) * 128; ++kk) accv += p[kk] * vbase[(size_t)kk * DMODEL];
    part[ch][d] = accv;
    __syncthreads();
    if (tid < HDIM) {
        float rv = (part[0][tid] + part[1][tid] + part[2][tid] + part[3][tid]) * inv;
        ctx[((size_t)(b * SEQ + qi) * DMODEL + h * HDIM + tid)] = rv;
    }
}

extern "C" void kernel_launch(void* const* d_in, const int* in_sizes, int n_in,
                              void* d_out, int out_size, void* d_ws, size_t ws_size,
                              hipStream_t stream) {
    const int*   x   = (const int*)d_in[0];
    const float* tok = (const float*)d_in[1];
    const float* pos = (const float*)d_in[2];
    const float* n1s = (const float*)d_in[3];
    const float* n1b = (const float*)d_in[4];
    const float* n2s = (const float*)d_in[5];
    const float* n2b = (const float*)d_in[6];
    const float* wq  = (const float*)d_in[7];
    const float* wk  = (const float*)d_in[8];
    const float* wv  = (const float*)d_in[9];
    const float* wo  = (const float*)d_in[10];
    const float* bo  = (const float*)d_in[11];
    const float* w1  = (const float*)d_in[12];
    const float* b1  = (const float*)d_in[13];
    const float* w2  = (const float*)d_in[14];
    const float* b2  = (const float*)d_in[15];
    const float* fs  = (const float*)d_in[16];
    const float* fb  = (const float*)d_in[17];
    const float* hw  = (const float*)d_in[18];
    const float* hb  = (const float*)d_in[19];
    float* out = (float*)d_out;

    const size_t szWtQKV = (size_t)NLAYER * 2304 * 768 * 2;
    const size_t szWtO   = (size_t)NLAYER * 768 * 768 * 2;
    const size_t szWt1   = (size_t)NLAYER * 3072 * 768 * 2;
    const size_t szWt2   = (size_t)NLAYER * 768 * 3072 * 2;
    const size_t szWtH   = (size_t)VOCAB * 768 * 2;
    const size_t szH     = (size_t)MROWS * DMODEL * 4;
    const size_t szHN    = (size_t)MROWS * DMODEL * 2;
    const size_t szQKV   = (size_t)MROWS * 2304 * 2;
    const size_t szCTX   = (size_t)MROWS * DMODEL * 2;
    const size_t szFF    = (size_t)MROWS * 3072 * 2;
    const size_t NEED = szWtQKV + szWtO + szWt1 + szWt2 + szWtH + szH + szHN + szQKV + szCTX + szFF;

    if (ws_size >= NEED) {
        char* p = (char*)d_ws;
        u16* WtQKV = (u16*)p; p += szWtQKV;
        u16* WtO   = (u16*)p; p += szWtO;
        u16* Wt1   = (u16*)p; p += szWt1;
        u16* Wt2   = (u16*)p; p += szWt2;
        u16* WtH   = (u16*)p; p += szWtH;
        float* h   = (float*)p; p += szH;
        u16* hn    = (u16*)p; p += szHN;
        u16* qkv   = (u16*)p; p += szQKV;
        u16* ctx   = (u16*)p; p += szCTX;
        u16* ff    = (u16*)p; p += szFF;

        transpose_qkvo<<<dim3(12, 12, 24), 256, 0, stream>>>(wq, wk, wv, wo, WtQKV, WtO);
        transpose_conv<<<dim3(48, 12, NLAYER), 256, 0, stream>>>(w1, Wt1, 768, 3072, 768 * 3072, 3072 * 768);
        transpose_conv<<<dim3(12, 48, NLAYER), 256, 0, stream>>>(w2, Wt2, 3072, 768, 3072 * 768, 768 * 3072);
        transpose_conv<<<dim3(500, 12, 1), 256, 0, stream>>>(hw, WtH, 768, VOCAB, 0, 0);

        embed_kernel<<<(MROWS * DMODEL + 255) / 256, 256, 0, stream>>>(x, tok, pos, h);

        for (int l = 0; l < NLAYER; ++l) {
            const u16* wtqkv = WtQKV + (size_t)l * 2304 * 768;
            const u16* wto   = WtO   + (size_t)l * 768 * 768;
            const u16* wt1   = Wt1   + (size_t)l * 3072 * 768;
            const u16* wt2   = Wt2   + (size_t)l * 768 * 3072;

            norm_kernel<true><<<MROWS, 256, 0, stream>>>(h, n1s + l * DMODEL, n1b + l * DMODEL, hn);
            gemm_sm<true,false,false,false,64,64><<<576, 256, 0, stream>>>(hn, wtqkv, nullptr, nullptr, qkv, MROWS, 2304, 768);
            attn_mfma<<<192, 256, 0, stream>>>(qkv, ctx);
            gemm_sm<false,true,true,false,32,64><<<384, 256, 0, stream>>>(ctx, wto, bo + l * DMODEL, h, h, MROWS, 768, 768);
            norm_kernel<true><<<MROWS, 256, 0, stream>>>(h, n2s + l * DMODEL, n2b + l * DMODEL, hn);
            gemm_sm<true,true,false,true,64,64><<<768, 256, 0, stream>>>(hn, wt1, b1 + (size_t)l * 3072, nullptr, ff, MROWS, 3072, 768);
            gemm_sm<false,true,true,false,32,64><<<384, 256, 0, stream>>>(ff, wt2, b2 + l * DMODEL, h, h, MROWS, 768, 3072);
        }
        norm_kernel<true><<<MROWS, 256, 0, stream>>>(h, fs, fb, hn);
        gemm_hd<<<2000, 256, 0, stream>>>(hn, WtH, hb, out, MROWS, VOCAB, 768);
        return;
    }

    // ---------- fp32 fallback ----------
    float* ws  = (float*)d_ws;
    float* h   = ws;
    float* hnf = h   + (size_t)MROWS * DMODEL;
    float* qb  = hnf + (size_t)MROWS * DMODEL;
    float* kb  = qb  + (size_t)MROWS * DMODEL;
    float* vb  = kb  + (size_t)MROWS * DMODEL;
    float* ctxf= vb  + (size_t)MROWS * DMODEL;
    float* fff = ctxf+ (size_t)MROWS * DMODEL;

    embed_kernel<<<(MROWS * DMODEL + 255) / 256, 256, 0, stream>>>(x, tok, pos, h);
    dim3 g768(DMODEL / 64, MROWS / 64);
    dim3 g3072(4 * DMODEL / 64, MROWS / 64);
    dim3 gV(VOCAB / 64, MROWS / 64);
    for (int l = 0; l < NLAYER; ++l) {
        size_t wOff  = (size_t)l * DMODEL * DMODEL;
        size_t w1Off = (size_t)l * DMODEL * 4 * DMODEL;
        norm_kernel<false><<<MROWS, 256, 0, stream>>>(h, n1s + l * DMODEL, n1b + l * DMODEL, hnf);
        gemm_f32<false,false,false><<<g768, 256, 0, stream>>>(hnf, wq + wOff, nullptr, nullptr, qb, MROWS, DMODEL, DMODEL);
        gemm_f32<false,false,false><<<g768, 256, 0, stream>>>(hnf, wk + wOff, nullptr, nullptr, kb, MROWS, DMODEL, DMODEL);
        gemm_f32<false,false,false><<<g768, 256, 0, stream>>>(hnf, wv + wOff, nullptr, nullptr, vb, MROWS, DMODEL, DMODEL);
        attn_f32<<<BDIM * NHEAD * SEQ, 256, 0, stream>>>(qb, kb, vb, ctxf);
        gemm_f32<true,true,false><<<g768, 256, 0, stream>>>(ctxf, wo + wOff, bo + l * DMODEL, h, h, MROWS, DMODEL, DMODEL);
        norm_kernel<false><<<MROWS, 256, 0, stream>>>(h, n2s + l * DMODEL, n2b + l * DMODEL, hnf);
        gemm_f32<true,false,true><<<g3072, 256, 0, stream>>>(hnf, w1 + w1Off, b1 + (size_t)l * 4 * DMODEL, nullptr, fff, MROWS, 4 * DMODEL, DMODEL);
        gemm_f32<true,true,false><<<g768, 256, 0, stream>>>(fff, w2 + w1Off, b2 + l * DMODEL, h, h, MROWS, DMODEL, 4 * DMODEL);
    }
    norm_kernel<false><<<MROWS, 256, 0, stream>>>(h, fs, fb, hnf);
    gemm_f32<true,false,false><<<gV, 256, 0, stream>>>(hnf, hw, hb, nullptr, out, MROWS, VOCAB, DMODEL);
}